// Round 1
// baseline (7584.723 us; speedup 1.0000x reference)
//
#include <hip/hip_runtime.h>
#include <math.h>

#define LN_EPS 1e-5f

// ---------------------------------------------------------------------------
// Kernel 1: per-window attention block.
// grid = 8192 (B=8 * 32 * 32 windows), block = 256
// Reads x (B,C,H,W), entropy_map (B,1,H,W); writes x_res in (B,H,W,C) to ws.
// ---------------------------------------------------------------------------
__global__ __launch_bounds__(256) void attn_kernel(
    const float* __restrict__ x,
    const float* __restrict__ emap,
    const float* __restrict__ beta_p,
    const float* __restrict__ wq, const float* __restrict__ bq,
    const float* __restrict__ wk, const float* __restrict__ bk,
    const float* __restrict__ wv, const float* __restrict__ bv,
    const float* __restrict__ wo, const float* __restrict__ bo,
    const float* __restrict__ g1, const float* __restrict__ b1,
    float* __restrict__ xres)
{
    const int C = 96, H = 224, W = 224, WS = 7, NW = 32, N = 49;

    __shared__ float xt_s[49][97];   // raw transposed window (residual)
    __shared__ float xn_s[49][97];   // LN1 output; later reused as attn output
    __shared__ float q_s[49][97];
    __shared__ float k_s[49][97];
    __shared__ float v_s[49][97];
    __shared__ float sc[49][50];     // per-head score/attn matrix
    __shared__ float ew_s[49];

    const int bw  = blockIdx.x;
    const int b   = bw / (NW * NW);
    const int rr0 = bw % (NW * NW);
    const int wh  = rr0 / NW, wwi = rr0 % NW;
    const int h0  = wh * WS, w0 = wwi * WS;
    const int tid = threadIdx.x;

    // ---- load x window (transposed read from (B,C,H,W)) ----
    for (int i = tid; i < N * C; i += 256) {
        int c = i / N, n = i % N;
        int hh = h0 + n / 7, ww = w0 + n % 7;
        xt_s[n][c] = x[((b * C + c) * H + hh) * W + ww];
    }
    if (tid < N) {
        int hh = h0 + tid / 7, ww = w0 + tid % 7;
        ew_s[tid] = emap[(b * H + hh) * W + ww];
    }
    __syncthreads();

    // ---- LN1 per token ----
    for (int t = tid; t < N; t += 256) {
        float s = 0.f, s2 = 0.f;
        for (int c = 0; c < C; c++) { float v = xt_s[t][c]; s += v; s2 += v * v; }
        float m    = s / C;
        float var  = s2 / C - m * m;
        float rstd = rsqrtf(var + LN_EPS);
        for (int c = 0; c < C; c++)
            xn_s[t][c] = (xt_s[t][c] - m) * rstd * g1[c] + b1[c];
    }
    __syncthreads();

    // ---- QKV: outputs (t,d); register-tile 7 t's per work-item ----
    // work item: d in [0,96), tg in [0,7) -> t = tg*7 + tt
    for (int wi = tid; wi < 96 * 7; wi += 256) {
        int d  = wi % 96;
        int tg = wi / 96;
        float aq[7], ak[7], av[7];
#pragma unroll
        for (int tt = 0; tt < 7; tt++) { aq[tt] = 0.f; ak[tt] = 0.f; av[tt] = 0.f; }
        for (int c = 0; c < C; c++) {
            float wqv = wq[c * 96 + d];
            float wkv = wk[c * 96 + d];
            float wvv = wv[c * 96 + d];
#pragma unroll
            for (int tt = 0; tt < 7; tt++) {
                float xv = xn_s[tg * 7 + tt][c];
                aq[tt] += xv * wqv;
                ak[tt] += xv * wkv;
                av[tt] += xv * wvv;
            }
        }
#pragma unroll
        for (int tt = 0; tt < 7; tt++) {
            int t = tg * 7 + tt;
            q_s[t][d] = aq[tt] + bq[d];
            k_s[t][d] = ak[tt] + bk[d];
            v_s[t][d] = av[tt] + bv[d];
        }
    }
    __syncthreads();

    const float beta  = beta_p[0];
    const float scale = rsqrtf(24.0f);

    // ---- per-head attention ----
    for (int hh = 0; hh < 4; hh++) {
        const int off = hh * 24;
        for (int i = tid; i < N * N; i += 256) {
            int qi = i / N, kj = i % N;
            float a = 0.f;
#pragma unroll
            for (int d = 0; d < 24; d++) a += q_s[qi][off + d] * k_s[kj][off + d];
            sc[qi][kj] = a * scale;
        }
        __syncthreads();
        // softmax + entropy gating + renormalize, per row
        for (int r = tid; r < N; r += 256) {
            float m = -1e30f;
            for (int j = 0; j < N; j++) m = fmaxf(m, sc[r][j]);
            float s = 0.f;
            for (int j = 0; j < N; j++) { float e = expf(sc[r][j] - m); sc[r][j] = e; s += e; }
            float g     = expf(-beta * ew_s[r]);
            // softmax_j = e_j/s ; gated = softmax_j*g ; denom = g*1 + 1e-9
            float inv   = g / (s * (g + 1e-9f));
            for (int j = 0; j < N; j++) sc[r][j] *= inv;
        }
        __syncthreads();
        // PV: out (t, off+d)
        for (int i = tid; i < N * 24; i += 256) {
            int t = i / 24, d = i % 24;
            float a = 0.f;
            for (int j = 0; j < N; j++) a += sc[t][j] * v_s[j][off + d];
            xn_s[t][off + d] = a;   // xn_s reused as attention output
        }
        __syncthreads();
    }

    // ---- output projection + residual; write (B,H,W,C) ----
    for (int wi = tid; wi < 96 * 7; wi += 256) {
        int c  = wi % 96;
        int tg = wi / 96;
        float a[7];
#pragma unroll
        for (int tt = 0; tt < 7; tt++) a[tt] = bo[c];
        for (int d = 0; d < C; d++) {
            float wov = wo[d * 96 + c];
#pragma unroll
            for (int tt = 0; tt < 7; tt++)
                a[tt] += xn_s[tg * 7 + tt][d] * wov;
        }
#pragma unroll
        for (int tt = 0; tt < 7; tt++) {
            int t  = tg * 7 + tt;
            int hh2 = h0 + t / 7, ww2 = w0 + t % 7;
            xres[((b * H + hh2) * W + ww2) * C + c] = xt_s[t][c] + a[tt];
        }
    }
}

// ---------------------------------------------------------------------------
// Kernel 2: MLP branch over 56-token row segments.
// grid = 8*224*4 = 7168, block = 256
// Reads x_res (B,H,W,C) from ws; writes final output (B,C,H,W).
// ---------------------------------------------------------------------------
__global__ __launch_bounds__(256) void mlp_kernel(
    const float* __restrict__ xres,
    const float* __restrict__ g2, const float* __restrict__ b2,
    const float* __restrict__ w1, const float* __restrict__ bf1,
    const float* __restrict__ w2, const float* __restrict__ bf2,
    float* __restrict__ out)
{
    const int C = 96, HID = 384, H = 224, W = 224, TW = 56;

    __shared__ float xr[TW][97];     // LN2-normalized segment
    __shared__ float hb[TW][385];    // hidden activations

    const int bid  = blockIdx.x;
    const int b    = bid / (H * 4);
    const int r    = bid % (H * 4);
    const int hrow = r / 4;
    const int wseg = r % 4;
    const int w0   = wseg * TW;
    const int tid  = threadIdx.x;

    const float* base = xres + ((size_t)(b * H + hrow) * W + w0) * C;

    for (int i = tid; i < TW * C; i += 256) {
        int t = i / C, c = i % C;
        xr[t][c] = base[t * C + c];
    }
    __syncthreads();

    // LN2 per token (normalized overwrites LDS; residual re-read from global)
    for (int t = tid; t < TW; t += 256) {
        float s = 0.f, s2 = 0.f;
        for (int c = 0; c < C; c++) { float v = xr[t][c]; s += v; s2 += v * v; }
        float m    = s / C;
        float var  = s2 / C - m * m;
        float rstd = rsqrtf(var + LN_EPS);
        for (int c = 0; c < C; c++)
            xr[t][c] = (xr[t][c] - m) * rstd * g2[c] + b2[c];
    }
    __syncthreads();

    // FC1 + exact GELU: outputs (t, j); tile 8 t's per work item (56 = 7*8)
    for (int wi = tid; wi < HID * 7; wi += 256) {
        int j  = wi % HID;
        int tg = wi / HID;
        float a[8];
#pragma unroll
        for (int tt = 0; tt < 8; tt++) a[tt] = bf1[j];
        for (int c = 0; c < C; c++) {
            float wv = w1[c * HID + j];
#pragma unroll
            for (int tt = 0; tt < 8; tt++)
                a[tt] += xr[tg * 8 + tt][c] * wv;
        }
#pragma unroll
        for (int tt = 0; tt < 8; tt++) {
            float v = a[tt];
            hb[tg * 8 + tt][j] = 0.5f * v * (1.0f + erff(v * 0.70710678118654752f));
        }
    }
    __syncthreads();

    // FC2 + residual + transposed write: outputs (c, t)
    for (int i = tid; i < TW * C; i += 256) {
        int c = i / TW, t = i % TW;   // consecutive tid -> consecutive t (coalesced store)
        float a = bf2[c];
        for (int j = 0; j < HID; j++) a += hb[t][j] * w2[j * C + c];
        float rv = base[t * C + c] + a;
        out[((size_t)(b * C + c) * H + hrow) * W + w0 + t] = rv;
    }
}

extern "C" void kernel_launch(void* const* d_in, const int* in_sizes, int n_in,
                              void* d_out, int out_size, void* d_ws, size_t ws_size,
                              hipStream_t stream) {
    const float* x    = (const float*)d_in[0];
    const float* emap = (const float*)d_in[1];
    const float* beta = (const float*)d_in[2];
    const float* wq   = (const float*)d_in[3];
    const float* bq   = (const float*)d_in[4];
    const float* wk   = (const float*)d_in[5];
    const float* bk   = (const float*)d_in[6];
    const float* wv   = (const float*)d_in[7];
    const float* bv   = (const float*)d_in[8];
    const float* wo   = (const float*)d_in[9];
    const float* bo   = (const float*)d_in[10];
    const float* g1   = (const float*)d_in[11];
    const float* b1   = (const float*)d_in[12];
    const float* g2   = (const float*)d_in[13];
    const float* b2   = (const float*)d_in[14];
    const float* w1   = (const float*)d_in[15];
    const float* bf1  = (const float*)d_in[16];
    const float* w2   = (const float*)d_in[17];
    const float* bf2  = (const float*)d_in[18];

    float* out  = (float*)d_out;
    float* xres = (float*)d_ws;   // (8,224,224,96) fp32 = 154.1 MB

    attn_kernel<<<dim3(8192), dim3(256), 0, stream>>>(
        x, emap, beta, wq, bq, wk, bk, wv, bv, wo, bo, g1, b1, xres);
    mlp_kernel<<<dim3(7168), dim3(256), 0, stream>>>(
        xres, g2, b2, w1, bf1, w2, bf2, out);
}

// Round 2
// 2521.348 us; speedup vs baseline: 3.0082x; 3.0082x over previous
//
#include <hip/hip_runtime.h>
#include <hip/hip_bf16.h>
#include <math.h>

#define LN_EPS 1e-5f

// ---------------------------------------------------------------------------
// Kernel 1: per-window attention block.
// grid = 8192 (B=8 * 32 * 32 windows), block = 256
// LDS: xt(19K) + xn(19K) + qkv bf16(28.8K) + sc(10.2K) = ~76KB -> 2 blocks/CU
// ---------------------------------------------------------------------------
__global__ __launch_bounds__(256) void attn_kernel(
    const float* __restrict__ x,
    const float* __restrict__ emap,
    const float* __restrict__ beta_p,
    const float* __restrict__ wq, const float* __restrict__ bq,
    const float* __restrict__ wk, const float* __restrict__ bk,
    const float* __restrict__ wv, const float* __restrict__ bv,
    const float* __restrict__ wo, const float* __restrict__ bo,
    const float* __restrict__ g1, const float* __restrict__ b1,
    float* __restrict__ xres)
{
    const int C = 96, H = 224, W = 224, WS = 7, NW = 32, N = 49;

    __shared__ float xt_s[49][97];           // raw transposed window (residual)
    __shared__ float xn_s[49][97];           // LN1 out; reused as attn output
    __shared__ __hip_bfloat16 q_s[49][98];   // stride 98 bf16 = 49 dwords (odd->conflict-free)
    __shared__ __hip_bfloat16 k_s[49][98];
    __shared__ __hip_bfloat16 v_s[49][98];
    __shared__ float sc[49][53];             // 53 dwords stride, odd -> conflict-free
    __shared__ float ew_s[49];

    const int bw  = blockIdx.x;
    const int b   = bw / (NW * NW);
    const int rr0 = bw % (NW * NW);
    const int wh  = rr0 / NW, wwi = rr0 % NW;
    const int h0  = wh * WS, w0 = wwi * WS;
    const int tid = threadIdx.x;

    // ---- load x window (transposed read from (B,C,H,W)) ----
    for (int i = tid; i < N * C; i += 256) {
        int c = i / N, n = i % N;
        int hh = h0 + n / 7, ww = w0 + n % 7;
        xt_s[n][c] = x[((b * C + c) * H + hh) * W + ww];
    }
    if (tid < N) {
        int hh = h0 + tid / 7, ww = w0 + tid % 7;
        ew_s[tid] = emap[(b * H + hh) * W + ww];
    }
    __syncthreads();

    // ---- LN1 per token ----
    for (int t = tid; t < N; t += 256) {
        float s = 0.f, s2 = 0.f;
        for (int c = 0; c < C; c++) { float v = xt_s[t][c]; s += v; s2 += v * v; }
        float m    = s / C;
        float var  = s2 / C - m * m;
        float rstd = rsqrtf(var + LN_EPS);
        for (int c = 0; c < C; c++)
            xn_s[t][c] = (xt_s[t][c] - m) * rstd * g1[c] + b1[c];
    }
    __syncthreads();

    // ---- QKV: outputs (t,d); register-tile 7 t's per work-item, bf16 store ----
    for (int wi = tid; wi < 96 * 7; wi += 256) {
        int d  = wi % 96;
        int tg = wi / 96;
        float aq[7], ak[7], av[7];
#pragma unroll
        for (int tt = 0; tt < 7; tt++) { aq[tt] = 0.f; ak[tt] = 0.f; av[tt] = 0.f; }
        for (int c = 0; c < C; c++) {
            float wqv = wq[c * 96 + d];
            float wkv = wk[c * 96 + d];
            float wvv = wv[c * 96 + d];
#pragma unroll
            for (int tt = 0; tt < 7; tt++) {
                float xv = xn_s[tg * 7 + tt][c];
                aq[tt] += xv * wqv;
                ak[tt] += xv * wkv;
                av[tt] += xv * wvv;
            }
        }
#pragma unroll
        for (int tt = 0; tt < 7; tt++) {
            int t = tg * 7 + tt;
            q_s[t][d] = __float2bfloat16(aq[tt] + bq[d]);
            k_s[t][d] = __float2bfloat16(ak[tt] + bk[d]);
            v_s[t][d] = __float2bfloat16(av[tt] + bv[d]);
        }
    }
    __syncthreads();

    const float beta  = beta_p[0];
    const float scale = rsqrtf(24.0f);

    // ---- per-head attention ----
    for (int hh = 0; hh < 4; hh++) {
        const int off = hh * 24;

        // scores: register-tile 7 queries per work item
        for (int wi = tid; wi < 7 * 49; wi += 256) {
            int kj = wi % 49, qg = wi / 49;
            float acc[7];
#pragma unroll
            for (int tt = 0; tt < 7; tt++) acc[tt] = 0.f;
#pragma unroll
            for (int d = 0; d < 24; d += 2) {
                __hip_bfloat162 kp = *reinterpret_cast<const __hip_bfloat162*>(&k_s[kj][off + d]);
                float kx = __bfloat162float(kp.x), ky = __bfloat162float(kp.y);
#pragma unroll
                for (int tt = 0; tt < 7; tt++) {
                    __hip_bfloat162 qp = *reinterpret_cast<const __hip_bfloat162*>(&q_s[qg * 7 + tt][off + d]);
                    acc[tt] += __bfloat162float(qp.x) * kx + __bfloat162float(qp.y) * ky;
                }
            }
#pragma unroll
            for (int tt = 0; tt < 7; tt++) sc[qg * 7 + tt][kj] = acc[tt] * scale;
        }
        __syncthreads();

        // softmax + gating + renormalize per row
        for (int r = tid; r < N; r += 256) {
            float m = -1e30f;
            for (int j = 0; j < N; j++) m = fmaxf(m, sc[r][j]);
            float s = 0.f;
            for (int j = 0; j < N; j++) { float e = expf(sc[r][j] - m); sc[r][j] = e; s += e; }
            float g   = expf(-beta * ew_s[r]);
            float inv = g / (s * (g + 1e-9f));
            for (int j = 0; j < N; j++) sc[r][j] *= inv;
        }
        __syncthreads();

        // PV: register-tile 7 tokens per work item
        for (int wi = tid; wi < 7 * 24; wi += 256) {
            int d = wi % 24, tg = wi / 24;
            float acc[7];
#pragma unroll
            for (int tt = 0; tt < 7; tt++) acc[tt] = 0.f;
            for (int j = 0; j < 49; j++) {
                float vv = __bfloat162float(v_s[j][off + d]);
#pragma unroll
                for (int tt = 0; tt < 7; tt++) acc[tt] += sc[tg * 7 + tt][j] * vv;
            }
#pragma unroll
            for (int tt = 0; tt < 7; tt++) xn_s[tg * 7 + tt][off + d] = acc[tt];
        }
        __syncthreads();
    }

    // ---- output projection + residual; write (B,H,W,C) ----
    for (int wi = tid; wi < 96 * 7; wi += 256) {
        int c  = wi % 96;
        int tg = wi / 96;
        float a[7];
#pragma unroll
        for (int tt = 0; tt < 7; tt++) a[tt] = bo[c];
        for (int d = 0; d < C; d++) {
            float wov = wo[d * 96 + c];
#pragma unroll
            for (int tt = 0; tt < 7; tt++)
                a[tt] += xn_s[tg * 7 + tt][d] * wov;
        }
#pragma unroll
        for (int tt = 0; tt < 7; tt++) {
            int t   = tg * 7 + tt;
            int hh2 = h0 + t / 7, ww2 = w0 + t % 7;
            xres[((b * H + hh2) * W + ww2) * C + c] = xt_s[t][c] + a[tt];
        }
    }
}

// ---------------------------------------------------------------------------
// Kernel 2: MLP branch, 56-token segments, hidden tiled 4x96.
// grid = 7168, block = 256. LDS = 43.5KB -> 3 blocks/CU.
// Thread tiling: (7 tokens x 3 cols) per thread = exactly 256 work items.
// ---------------------------------------------------------------------------
__global__ __launch_bounds__(256) void mlp_kernel(
    const float* __restrict__ xres,
    const float* __restrict__ g2, const float* __restrict__ b2,
    const float* __restrict__ w1, const float* __restrict__ bf1,
    const float* __restrict__ w2, const float* __restrict__ bf2,
    float* __restrict__ out)
{
    const int C = 96, HID = 384, H = 224, W = 224, T = 56;

    __shared__ float xr[T][97];   // LN2-normalized segment; reused for output staging
    __shared__ float hb[T][97];   // hidden tile (96 wide)

    const int bid  = blockIdx.x;
    const int b    = bid / (H * 4);
    const int r    = bid % (H * 4);
    const int hrow = r / 4;
    const int wseg = r % 4;
    const int w0   = wseg * T;
    const int tid  = threadIdx.x;

    const float* base = xres + ((size_t)(b * H + hrow) * W + w0) * C;

    for (int i = tid; i < T * C; i += 256) {
        int t = i / C, c = i % C;
        xr[t][c] = base[i];
    }
    __syncthreads();

    // LN2 per token, in place
    for (int t = tid; t < T; t += 256) {
        float s = 0.f, s2 = 0.f;
        for (int c = 0; c < C; c++) { float v = xr[t][c]; s += v; s2 += v * v; }
        float m    = s / C;
        float var  = s2 / C - m * m;
        float rstd = rsqrtf(var + LN_EPS);
        for (int c = 0; c < C; c++)
            xr[t][c] = (xr[t][c] - m) * rstd * g2[c] + b2[c];
    }
    __syncthreads();

    const int jg = tid & 31;   // column group (32 groups of 3)
    const int tg = tid >> 5;   // token group (8 groups of 7)
    const int t0 = tg * 7;
    const int j0 = jg * 3;

    float acc[7][3];
#pragma unroll
    for (int tt = 0; tt < 7; tt++)
#pragma unroll
        for (int jj = 0; jj < 3; jj++) acc[tt][jj] = 0.f;

    for (int jt = 0; jt < 4; jt++) {
        // ---- FC1 tile: hidden cols [jt*96 + j0 .. +2], 7 tokens ----
        float a[7][3];
#pragma unroll
        for (int tt = 0; tt < 7; tt++)
#pragma unroll
            for (int jj = 0; jj < 3; jj++) a[tt][jj] = bf1[jt * 96 + j0 + jj];
        for (int c = 0; c < C; c++) {
            const float* w1p = &w1[c * HID + jt * 96 + j0];
            float w1v0 = w1p[0], w1v1 = w1p[1], w1v2 = w1p[2];
#pragma unroll
            for (int tt = 0; tt < 7; tt++) {
                float xv = xr[t0 + tt][c];
                a[tt][0] += xv * w1v0;
                a[tt][1] += xv * w1v1;
                a[tt][2] += xv * w1v2;
            }
        }
#pragma unroll
        for (int tt = 0; tt < 7; tt++)
#pragma unroll
            for (int jj = 0; jj < 3; jj++) {
                float v = a[tt][jj];
                hb[t0 + tt][j0 + jj] = 0.5f * v * (1.0f + erff(v * 0.70710678118654752f));
            }
        __syncthreads();

        // ---- FC2 partial: out cols [j0..j0+2], accumulate over this hidden tile ----
        for (int j = 0; j < 96; j++) {
            const float* w2p = &w2[(size_t)(jt * 96 + j) * C + j0];
            float w2v0 = w2p[0], w2v1 = w2p[1], w2v2 = w2p[2];
#pragma unroll
            for (int tt = 0; tt < 7; tt++) {
                float hv = hb[t0 + tt][j];
                acc[tt][0] += hv * w2v0;
                acc[tt][1] += hv * w2v1;
                acc[tt][2] += hv * w2v2;
            }
        }
        __syncthreads();
    }

    // ---- epilogue: residual + bias, stage in LDS, coalesced transposed write ----
#pragma unroll
    for (int tt = 0; tt < 7; tt++)
#pragma unroll
        for (int jj = 0; jj < 3; jj++)
            xr[t0 + tt][j0 + jj] = acc[tt][jj] + bf2[j0 + jj] + base[(t0 + tt) * C + j0 + jj];
    __syncthreads();

    for (int i = tid; i < T * C; i += 256) {
        int c = i / T, t = i % T;   // consecutive tid -> consecutive t -> coalesced store
        out[((size_t)(b * C + c) * H + hrow) * W + w0 + t] = xr[t][c];
    }
}

extern "C" void kernel_launch(void* const* d_in, const int* in_sizes, int n_in,
                              void* d_out, int out_size, void* d_ws, size_t ws_size,
                              hipStream_t stream) {
    const float* x    = (const float*)d_in[0];
    const float* emap = (const float*)d_in[1];
    const float* beta = (const float*)d_in[2];
    const float* wq   = (const float*)d_in[3];
    const float* bq   = (const float*)d_in[4];
    const float* wk   = (const float*)d_in[5];
    const float* bk   = (const float*)d_in[6];
    const float* wv   = (const float*)d_in[7];
    const float* bv   = (const float*)d_in[8];
    const float* wo   = (const float*)d_in[9];
    const float* bo   = (const float*)d_in[10];
    const float* g1   = (const float*)d_in[11];
    const float* b1   = (const float*)d_in[12];
    const float* g2   = (const float*)d_in[13];
    const float* b2   = (const float*)d_in[14];
    const float* w1   = (const float*)d_in[15];
    const float* bf1  = (const float*)d_in[16];
    const float* w2   = (const float*)d_in[17];
    const float* bf2  = (const float*)d_in[18];

    float* out  = (float*)d_out;
    float* xres = (float*)d_ws;   // (8,224,224,96) fp32 = 154.1 MB

    attn_kernel<<<dim3(8192), dim3(256), 0, stream>>>(
        x, emap, beta, wq, bq, wk, bk, wv, bv, wo, bo, g1, b1, xres);
    mlp_kernel<<<dim3(7168), dim3(256), 0, stream>>>(
        xres, g2, b2, w1, bf1, w2, bf2, out);
}

// Round 3
// 663.245 us; speedup vs baseline: 11.4358x; 3.8015x over previous
//
#include <hip/hip_runtime.h>
#include <math.h>

typedef __attribute__((ext_vector_type(8))) short short8;
typedef __attribute__((ext_vector_type(4))) float f32x4;
typedef __attribute__((ext_vector_type(4))) unsigned int uint4v;

struct __align__(8) U2 { unsigned int x, y; };

#define DEVI static __device__ __forceinline__

DEVI unsigned pk1(float f){ unsigned u = __float_as_uint(f); return (u + 0x7fffu + ((u>>16)&1u)) >> 16; }
DEVI unsigned pk2(float a, float b){ return pk1(a) | (pk1(b) << 16); }
DEVI float bfu(unsigned hs){ return __uint_as_float((hs & 0xffffu) << 16); }

DEVI short8 lds8(const unsigned short* p){
  union { short8 v; U2 u[2]; } f;
  f.u[0] = *(const U2*)p;
  f.u[1] = *(const U2*)(p + 4);
  return f.v;
}
DEVI short8 zero8(){ union { short8 v; U2 u[2]; } f; f.u[0].x=0; f.u[0].y=0; f.u[1].x=0; f.u[1].y=0; return f.v; }
DEVI short8 gfrag(const unsigned short* p){ union { short8 v; uint4v u; } f; f.u = *(const uint4v*)p; return f.v; }
DEVI f32x4 MFMA(short8 a, short8 b, f32x4 c){ return __builtin_amdgcn_mfma_f32_16x16x32_bf16(a, b, c, 0, 0, 0); }
DEVI void st2(unsigned short* p, unsigned lo, unsigned hi){ U2 t; t.x = lo; t.y = hi; *(U2*)p = t; }

// ---------------------------------------------------------------------------
// prep: swizzle all weights into bf16 MFMA fragment arrays in ws.
// Fragment element map (same map used by ALL consumers, so any K-permutation
// uncertainty cancels): m/n = 16*mt + (lane&15), k = 32*kb + 8*(lane>>4) + j.
// Offsets (ushort elems): AQT=0, AKT=9216, BV=18432, AOT=27648,
//                         A1T=36864 (24 mt x 3 kb), A2T=73728 (6 mt x 12 kb)
// ---------------------------------------------------------------------------
__global__ __launch_bounds__(256) void prep_kernel(
    const float* __restrict__ wq, const float* __restrict__ wk,
    const float* __restrict__ wv, const float* __restrict__ wo,
    const float* __restrict__ w1, const float* __restrict__ w2,
    unsigned short* __restrict__ wfr)
{
  int i = blockIdx.x * 256 + threadIdx.x;
  if (i >= 110592) return;
  int j = i & 7, lane = (i >> 3) & 63, fr = i >> 9;
  int ln = lane & 15, lg = lane >> 4;
  float v;
  if (fr < 18)      { int s = fr;       int mt = s/3,  kb = s%3;  v = wq[(32*kb + 8*lg + j)*96  + 16*mt + ln]; }
  else if (fr < 36) { int s = fr - 18;  int mt = s/3,  kb = s%3;  v = wk[(32*kb + 8*lg + j)*96  + 16*mt + ln]; }
  else if (fr < 54) { int s = fr - 36;  int nt = s/3,  kb = s%3;  v = wv[(32*kb + 8*lg + j)*96  + 16*nt + ln]; }
  else if (fr < 72) { int s = fr - 54;  int mt = s/3,  kb = s%3;  v = wo[(32*kb + 8*lg + j)*96  + 16*mt + ln]; }
  else if (fr < 144){ int s = fr - 72;  int mt = s/3,  kb = s%3;  v = w1[(32*kb + 8*lg + j)*384 + 16*mt + ln]; }
  else              { int s = fr - 144; int mt = s/12, kb = s%12; v = w2[(32*kb + 8*lg + j)*96  + 16*mt + ln]; }
  wfr[i] = (unsigned short)pk1(v);
}

// ---------------------------------------------------------------------------
// Fused Swin block: one 7x7 window per block (tokens padded 49->64), 256 thr.
// LDS (77056 B, 2 blocks/CU): XT | UA(xn->o_s) | UB(q_s->xres) | UC(k_s->xn2)
//                             | UD(vT+p_s -> h_s) | ew
// ---------------------------------------------------------------------------
__global__ __launch_bounds__(256) void swin_fused(
    const float* __restrict__ x, const float* __restrict__ emap,
    const float* __restrict__ beta_p,
    const float* __restrict__ bq, const float* __restrict__ bk,
    const float* __restrict__ bv, const float* __restrict__ bo,
    const float* __restrict__ g1, const float* __restrict__ b1,
    const float* __restrict__ g2, const float* __restrict__ b2,
    const float* __restrict__ bf1, const float* __restrict__ bf2,
    const unsigned short* __restrict__ wfr,
    float* __restrict__ out)
{
  __shared__ __align__(16) char smem[77056];
  unsigned short* XT = (unsigned short*)(smem);           // [64][100] bf16 raw window
  unsigned short* UA = (unsigned short*)(smem + 12800);   // xn [64][100] -> o_s [64][100]
  unsigned short* UB = (unsigned short*)(smem + 25600);   // q_s [64][100] -> xres [64][100]
  unsigned short* UC = (unsigned short*)(smem + 38400);   // k_s [64][100] -> xn2 [64][100]
  unsigned short* UD = (unsigned short*)(smem + 51200);   // vT[104][68] + p_s[64][68] -> h_s[64][200]
  unsigned short* VT = UD;
  unsigned short* PS = UD + 104*68;
  unsigned short* HS = UD;
  float* EWF = (float*)(smem + 76800);

  const int tid = threadIdx.x;
  const int lane = tid & 63;
  const int w   = tid >> 6;     // wave id 0..3
  const int lg  = lane >> 4;    // k-group
  const int ln  = lane & 15;    // m/n lane

  // XCD swizzle: each XCD gets 1024 contiguous windows (one image)
  int bid = blockIdx.x;
  int bw  = ((bid & 7) << 10) | (bid >> 3);
  const int b  = bw >> 10;
  const int rr = bw & 1023;
  const int h0 = (rr >> 5) * 7;
  const int w0 = (rr & 31) * 7;

  // ---- phase 0: load window -> XT (bf16), zero pads, ew ----
  for (int i = tid; i < 49*96; i += 256){
    int c = i / 49, n = i % 49;
    float v = x[(size_t)(b*96 + c)*50176 + (size_t)(h0 + n/7)*224 + w0 + n%7];
    XT[n*100 + c] = (unsigned short)pk1(v);
  }
  for (int i = tid; i < 15*100; i += 256){
    XT[(49 + i/100)*100 + i%100] = 0;
    UA[(49 + i/100)*100 + i%100] = 0;     // xn pad rows must be exact zero
  }
  for (int i = tid; i < 8*68; i += 256) VT[(96 + i/68)*68 + i%68] = 0;
  if (tid < 64)
    EWF[tid] = (tid < 49) ? emap[(size_t)b*50176 + (size_t)(h0 + tid/7)*224 + w0 + tid%7] : 0.f;
  __syncthreads();

  // ---- phase 1: LN1 -> xn (UA) ----
  if (tid < 49){
    const unsigned int* r32 = (const unsigned int*)(XT + tid*100);
    float s = 0.f, s2 = 0.f;
    for (int i = 0; i < 48; ++i){
      unsigned u = r32[i]; float a = bfu(u), c2 = bfu(u >> 16);
      s += a + c2; s2 += a*a + c2*c2;
    }
    float m = s * (1.f/96.f);
    float var = s2 * (1.f/96.f) - m*m;
    float rstd = rsqrtf(var + 1e-5f);
    unsigned int* w32 = (unsigned int*)(UA + tid*100);
    for (int i = 0; i < 48; ++i){
      unsigned u = r32[i];
      w32[i] = pk2((bfu(u)     - m)*rstd*g1[2*i]   + b1[2*i],
                   (bfu(u>>16) - m)*rstd*g1[2*i+1] + b1[2*i+1]);
    }
  }
  __syncthreads();

  // ---- phase 2: QKV.  Q^T=Wq^T·Xn^T, K^T likewise (acc packs d); V=Xn·Wv (acc packs tok) ----
  {
    short8 bx0 = lds8(UA + (16*w+ln)*100 + 0  + 8*lg);
    short8 bx1 = lds8(UA + (16*w+ln)*100 + 32 + 8*lg);
    short8 bx2 = lds8(UA + (16*w+ln)*100 + 64 + 8*lg);
#pragma unroll
    for (int mt = 0; mt < 6; ++mt){
      int d0 = 16*mt + 4*lg;
      f32x4 aq, ak;
#pragma unroll
      for (int r = 0; r < 4; ++r){ aq[r] = bq[d0+r]; ak[r] = bk[d0+r]; }
      aq = MFMA(gfrag(wfr +        (mt*3+0)*512 + lane*8), bx0, aq);
      aq = MFMA(gfrag(wfr +        (mt*3+1)*512 + lane*8), bx1, aq);
      aq = MFMA(gfrag(wfr +        (mt*3+2)*512 + lane*8), bx2, aq);
      ak = MFMA(gfrag(wfr + 9216 + (mt*3+0)*512 + lane*8), bx0, ak);
      ak = MFMA(gfrag(wfr + 9216 + (mt*3+1)*512 + lane*8), bx1, ak);
      ak = MFMA(gfrag(wfr + 9216 + (mt*3+2)*512 + lane*8), bx2, ak);
      st2(UB + (16*w+ln)*100 + d0, pk2(aq[0],aq[1]), pk2(aq[2],aq[3]));   // q_s[tok][d]
      st2(UC + (16*w+ln)*100 + d0, pk2(ak[0],ak[1]), pk2(ak[2],ak[3]));   // k_s[tok][d]
    }
#pragma unroll
    for (int f = 0; f < 6; ++f){
      int fl = f*4 + w;
      int mt = fl / 6, nt = fl % 6;
      float bvv = bv[16*nt + ln];
      f32x4 av; av[0]=bvv; av[1]=bvv; av[2]=bvv; av[3]=bvv;
#pragma unroll
      for (int kb = 0; kb < 3; ++kb)
        av = MFMA(lds8(UA + (16*mt+ln)*100 + 32*kb + 8*lg),
                  gfrag(wfr + 18432 + (nt*3+kb)*512 + lane*8), av);
      st2(VT + (16*nt+ln)*68 + 16*mt + 4*lg, pk2(av[0],av[1]), pk2(av[2],av[3]));  // vT[d][tok]
    }
  }
  __syncthreads();

  // ---- phase 3: per-head attention ----
  const float beta  = beta_p[0];
  const float scale = 0.20412414523193150818f;   // 1/sqrt(24)
  const float gq = __expf(-beta * EWF[16*w + ln]);  // gating for this lane's query

  for (int h = 0; h < 4; ++h){
    // scores S^T = K·Q^T : rows=keys(mt), cols=queries(nt=w). K-dim 24 padded to 32: lg==3 zeroed both sides.
    short8 bqf = (lg < 3) ? lds8(UB + (16*w+ln)*100 + 24*h + 8*lg) : zero8();
    f32x4 sv[4];
#pragma unroll
    for (int mt = 0; mt < 4; ++mt){
      short8 af = (lg < 3) ? lds8(UC + (16*mt+ln)*100 + 24*h + 8*lg) : zero8();
      f32x4 z; z[0]=0; z[1]=0; z[2]=0; z[3]=0;
      sv[mt] = MFMA(af, bqf, z);
    }
    // softmax over keys: 16 in-lane values + shfl_xor over lane groups (16,32)
    float vv[16]; float mx = -3e38f;
#pragma unroll
    for (int mt = 0; mt < 4; ++mt)
#pragma unroll
      for (int r = 0; r < 4; ++r){
        int key = 16*mt + 4*lg + r;
        float v = (key <= 48) ? sv[mt][r]*scale : -3e38f;
        vv[mt*4+r] = v; mx = fmaxf(mx, v);
      }
    mx = fmaxf(mx, __shfl_xor(mx, 16));
    mx = fmaxf(mx, __shfl_xor(mx, 32));
    float s = 0.f;
#pragma unroll
    for (int i = 0; i < 16; ++i){ float e = __expf(vv[i] - mx); vv[i] = e; s += e; }
    s += __shfl_xor(s, 16);
    s += __shfl_xor(s, 32);
    float inv = gq / (s * (gq + 1e-9f));
#pragma unroll
    for (int mt = 0; mt < 4; ++mt)
      st2(PS + (16*w+ln)*68 + 16*mt + 4*lg,
          pk2(vv[mt*4+0]*inv, vv[mt*4+1]*inv), pk2(vv[mt*4+2]*inv, vv[mt*4+3]*inv));
    __syncthreads();

    // PV^T = V^T·P^T : acc rows = d_local (packs into o_s[q][d]), cols = q
    short8 bp0 = lds8(PS + (16*w+ln)*68 + 0  + 8*lg);
    short8 bp1 = lds8(PS + (16*w+ln)*68 + 32 + 8*lg);
#pragma unroll
    for (int mt = 0; mt < 2; ++mt){
      f32x4 pv; pv[0]=0; pv[1]=0; pv[2]=0; pv[3]=0;
      pv = MFMA(lds8(VT + (24*h+16*mt+ln)*68 + 0  + 8*lg), bp0, pv);
      pv = MFMA(lds8(VT + (24*h+16*mt+ln)*68 + 32 + 8*lg), bp1, pv);
      if (!(mt == 1 && lg >= 2))     // d_local must stay < 24
        st2(UA + (16*w+ln)*100 + 24*h + 16*mt + 4*lg, pk2(pv[0],pv[1]), pk2(pv[2],pv[3]));
    }
    __syncthreads();
  }

  // ---- phase 4: proj^T = Wo^T·O^T, + residual -> xres (UB) ----
  {
    f32x4 po[6];
#pragma unroll
    for (int mt = 0; mt < 6; ++mt){
      int c0 = 16*mt + 4*lg;
#pragma unroll
      for (int r = 0; r < 4; ++r) po[mt][r] = bo[c0+r];
    }
#pragma unroll
    for (int kb = 0; kb < 3; ++kb){
      short8 bf_ = lds8(UA + (16*w+ln)*100 + 32*kb + 8*lg);
#pragma unroll
      for (int mt = 0; mt < 6; ++mt)
        po[mt] = MFMA(gfrag(wfr + 27648 + (mt*3+kb)*512 + lane*8), bf_, po[mt]);
    }
#pragma unroll
    for (int mt = 0; mt < 6; ++mt){
      int c0 = 16*mt + 4*lg;
      U2 xtp = *(const U2*)(XT + (16*w+ln)*100 + c0);
      st2(UB + (16*w+ln)*100 + c0,
          pk2(po[mt][0] + bfu(xtp.x), po[mt][1] + bfu(xtp.x >> 16)),
          pk2(po[mt][2] + bfu(xtp.y), po[mt][3] + bfu(xtp.y >> 16)));
    }
  }
  __syncthreads();

  // ---- phase 5: LN2 -> xn2 (UC) ----
  if (tid < 64){
    const unsigned int* r32 = (const unsigned int*)(UB + tid*100);
    float s = 0.f, s2 = 0.f;
    for (int i = 0; i < 48; ++i){
      unsigned u = r32[i]; float a = bfu(u), c2 = bfu(u >> 16);
      s += a + c2; s2 += a*a + c2*c2;
    }
    float m = s * (1.f/96.f);
    float var = s2 * (1.f/96.f) - m*m;
    float rstd = rsqrtf(var + 1e-5f);
    unsigned int* w32 = (unsigned int*)(UC + tid*100);
    for (int i = 0; i < 48; ++i){
      unsigned u = r32[i];
      w32[i] = pk2((bfu(u)     - m)*rstd*g2[2*i]   + b2[2*i],
                   (bfu(u>>16) - m)*rstd*g2[2*i+1] + b2[2*i+1]);
    }
  }
  __syncthreads();

  // ---- phase 6: MLP.  FC1^T = W1^T·Xn2^T (+GELU) -> h_s; FC2^T = W2^T·H^T accum ----
  f32x4 oacc[6];
#pragma unroll
  for (int mt = 0; mt < 6; ++mt){
    int c0 = 16*mt + 4*lg;
#pragma unroll
    for (int r = 0; r < 4; ++r) oacc[mt][r] = bf2[c0+r];
  }

  for (int p = 0; p < 2; ++p){
    short8 bxx0 = lds8(UC + (16*w+ln)*100 + 0  + 8*lg);
    short8 bxx1 = lds8(UC + (16*w+ln)*100 + 32 + 8*lg);
    short8 bxx2 = lds8(UC + (16*w+ln)*100 + 64 + 8*lg);
#pragma unroll
    for (int mt = 0; mt < 12; ++mt){
      int hg = p*192 + 16*mt + 4*lg;
      f32x4 ha;
#pragma unroll
      for (int r = 0; r < 4; ++r) ha[r] = bf1[hg+r];
      ha = MFMA(gfrag(wfr + 36864 + ((p*12+mt)*3+0)*512 + lane*8), bxx0, ha);
      ha = MFMA(gfrag(wfr + 36864 + ((p*12+mt)*3+1)*512 + lane*8), bxx1, ha);
      ha = MFMA(gfrag(wfr + 36864 + ((p*12+mt)*3+2)*512 + lane*8), bxx2, ha);
      float e0 = 0.5f*ha[0]*(1.f + erff(ha[0]*0.70710678118654752f));
      float e1 = 0.5f*ha[1]*(1.f + erff(ha[1]*0.70710678118654752f));
      float e2 = 0.5f*ha[2]*(1.f + erff(ha[2]*0.70710678118654752f));
      float e3 = 0.5f*ha[3]*(1.f + erff(ha[3]*0.70710678118654752f));
      st2(HS + (16*w+ln)*200 + 16*mt + 4*lg, pk2(e0,e1), pk2(e2,e3));
    }
    __syncthreads();
#pragma unroll
    for (int kb = 0; kb < 6; ++kb){
      short8 bh = lds8(HS + (16*w+ln)*200 + 32*kb + 8*lg);
#pragma unroll
      for (int mt = 0; mt < 6; ++mt)
        oacc[mt] = MFMA(gfrag(wfr + 73728 + (mt*12 + p*6 + kb)*512 + lane*8), bh, oacc[mt]);
    }
    __syncthreads();
  }

  // ---- phase 7: final residual + transposed store to (B,C,H,W) ----
  {
    int tok = 16*w + ln;
    if (tok < 49){
      size_t sp = (size_t)(h0 + tok/7)*224 + w0 + tok%7;
#pragma unroll
      for (int mt = 0; mt < 6; ++mt){
        int c0 = 16*mt + 4*lg;
        U2 xr = *(const U2*)(UB + tok*100 + c0);
        float* o0 = out + (size_t)(b*96 + c0)*50176 + sp;
        o0[0]      = oacc[mt][0] + bfu(xr.x);
        o0[50176]  = oacc[mt][1] + bfu(xr.x >> 16);
        o0[100352] = oacc[mt][2] + bfu(xr.y);
        o0[150528] = oacc[mt][3] + bfu(xr.y >> 16);
      }
    }
  }
}

extern "C" void kernel_launch(void* const* d_in, const int* in_sizes, int n_in,
                              void* d_out, int out_size, void* d_ws, size_t ws_size,
                              hipStream_t stream) {
  const float* x    = (const float*)d_in[0];
  const float* emap = (const float*)d_in[1];
  const float* beta = (const float*)d_in[2];
  const float* wq   = (const float*)d_in[3];
  const float* bq   = (const float*)d_in[4];
  const float* wk   = (const float*)d_in[5];
  const float* bk   = (const float*)d_in[6];
  const float* wv   = (const float*)d_in[7];
  const float* bv   = (const float*)d_in[8];
  const float* wo   = (const float*)d_in[9];
  const float* bo   = (const float*)d_in[10];
  const float* g1   = (const float*)d_in[11];
  const float* b1   = (const float*)d_in[12];
  const float* g2   = (const float*)d_in[13];
  const float* b2   = (const float*)d_in[14];
  const float* w1   = (const float*)d_in[15];
  const float* bf1  = (const float*)d_in[16];
  const float* w2   = (const float*)d_in[17];
  const float* bf2  = (const float*)d_in[18];

  float* out = (float*)d_out;
  unsigned short* wfr = (unsigned short*)d_ws;   // 110592 bf16 = 221 KB fragment store

  prep_kernel<<<dim3(432), dim3(256), 0, stream>>>(wq, wk, wv, wo, w1, w2, wfr);
  swin_fused<<<dim3(8192), dim3(256), 0, stream>>>(
      x, emap, beta, bq, bk, bv, bo, g1, b1, g2, b2, bf1, bf2, wfr, out);
}

// Round 4
// 421.622 us; speedup vs baseline: 17.9894x; 1.5731x over previous
//
#include <hip/hip_runtime.h>
#include <math.h>

typedef __attribute__((ext_vector_type(8))) short short8;
typedef __attribute__((ext_vector_type(4))) float f32x4;
typedef __attribute__((ext_vector_type(4))) unsigned int uint4v;

struct __align__(8) U2 { unsigned int x, y; };

#define DEVI static __device__ __forceinline__

DEVI unsigned pk1(float f){ unsigned u = __float_as_uint(f); return (u + 0x7fffu + ((u>>16)&1u)) >> 16; }
DEVI unsigned pk2(float a, float b){ return pk1(a) | (pk1(b) << 16); }
DEVI float bfu(unsigned hs){ return __uint_as_float((hs & 0xffffu) << 16); }

DEVI short8 lds8(const unsigned short* p){
  union { short8 v; U2 u[2]; } f;
  f.u[0] = *(const U2*)p;
  f.u[1] = *(const U2*)(p + 4);
  return f.v;
}
DEVI short8 mk8(unsigned a, unsigned b, unsigned c, unsigned d){
  union { short8 v; unsigned u[4]; } f; f.u[0]=a; f.u[1]=b; f.u[2]=c; f.u[3]=d; return f.v;
}
DEVI short8 zero8(){ return mk8(0,0,0,0); }
DEVI short8 gfrag(const unsigned short* p){ union { short8 v; uint4v u; } f; f.u = *(const uint4v*)p; return f.v; }
DEVI f32x4 MFMA(short8 a, short8 b, f32x4 c){ return __builtin_amdgcn_mfma_f32_16x16x32_bf16(a, b, c, 0, 0, 0); }
DEVI void st2(unsigned short* p, unsigned lo, unsigned hi){ U2 t; t.x=lo; t.y=hi; *(U2*)p = t; }

// ---------------------------------------------------------------------------
// prep: swizzle all weights into bf16 MFMA fragment arrays in ws.
// Fragment map (same map for ALL consumers, so K-permutation cancels):
// m/n = 16*mt + (lane&15), k = 32*kb + 8*(lane>>4) + j.
// Offsets (ushort): AQT=0, AKT=9216, BV=18432, AOT=27648, A1T=36864, A2T=73728
// ---------------------------------------------------------------------------
__global__ __launch_bounds__(256) void prep_kernel(
    const float* __restrict__ wq, const float* __restrict__ wk,
    const float* __restrict__ wv, const float* __restrict__ wo,
    const float* __restrict__ w1, const float* __restrict__ w2,
    unsigned short* __restrict__ wfr)
{
  int i = blockIdx.x * 256 + threadIdx.x;
  if (i >= 110592) return;
  int j = i & 7, lane = (i >> 3) & 63, fr = i >> 9;
  int ln = lane & 15, lg = lane >> 4;
  float v;
  if (fr < 18)      { int s = fr;       int mt = s/3,  kb = s%3;  v = wq[(32*kb + 8*lg + j)*96  + 16*mt + ln]; }
  else if (fr < 36) { int s = fr - 18;  int mt = s/3,  kb = s%3;  v = wk[(32*kb + 8*lg + j)*96  + 16*mt + ln]; }
  else if (fr < 54) { int s = fr - 36;  int nt = s/3,  kb = s%3;  v = wv[(32*kb + 8*lg + j)*96  + 16*nt + ln]; }
  else if (fr < 72) { int s = fr - 54;  int mt = s/3,  kb = s%3;  v = wo[(32*kb + 8*lg + j)*96  + 16*mt + ln]; }
  else if (fr < 144){ int s = fr - 72;  int mt = s/3,  kb = s%3;  v = w1[(32*kb + 8*lg + j)*384 + 16*mt + ln]; }
  else              { int s = fr - 144; int mt = s/12, kb = s%12; v = w2[(32*kb + 8*lg + j)*96  + 16*mt + ln]; }
  wfr[i] = (unsigned short)pk1(v);
}

// ---------------------------------------------------------------------------
// Attention kernel: one 7x7 window per block, 4 waves. 2 barriers total.
// LDS 52.8KB -> 3 blocks/CU. Writes xres (bf16, pixel-flat [pix][96]) to ws.
// ---------------------------------------------------------------------------
__global__ __launch_bounds__(256, 3) void attn_kernel(
    const float* __restrict__ x, const float* __restrict__ emap,
    const float* __restrict__ beta_p,
    const float* __restrict__ bq, const float* __restrict__ bk,
    const float* __restrict__ bv, const float* __restrict__ bo,
    const float* __restrict__ g1, const float* __restrict__ b1,
    const unsigned short* __restrict__ wfr,
    unsigned short* __restrict__ xres)
{
  __shared__ __align__(16) char smem[52800];
  unsigned short* XN = (unsigned short*)(smem);            // [64][100] xn -> o_s
  unsigned short* QS = (unsigned short*)(smem + 12800);    // [64][100] q
  unsigned short* KS = (unsigned short*)(smem + 25600);    // [64][100] k
  unsigned short* VT = (unsigned short*)(smem + 38400);    // [104][68] v^T
  float* EWF = (float*)(smem + 52544);                     // [64]

  const int tid = threadIdx.x;
  const int lane = tid & 63;
  const int w = tid >> 6, lg = lane >> 4, ln = lane & 15;

  int bid = blockIdx.x;
  int bw  = ((bid & 7) << 10) | (bid >> 3);   // XCD swizzle: one image per XCD
  const int b  = bw >> 10;
  const int rr = bw & 1023;
  const int h0 = (rr >> 5) * 7;
  const int w0 = (rr & 31) * 7;

  // ---- ph0: VT pad rows + entropy ----
  for (int i = tid; i < 8*68; i += 256) VT[(96 + i/68)*68 + i%68] = 0;
  if (tid < 64)
    EWF[tid] = (tid < 49) ? emap[(size_t)b*50176 + (size_t)(h0 + tid/7)*224 + w0 + tid%7] : 0.f;

  // ---- ph1: x -> regs, LN1 -> XN (own rows) ----
  {
    const int t = 16*w + ln;
    float xv[24];
    if (t < 49){
      size_t pixloc = (size_t)(h0 + t/7)*224 + w0 + t%7;
      const float* xp = x + (size_t)(b*96 + 24*lg)*50176 + pixloc;
#pragma unroll
      for (int i = 0; i < 24; ++i) xv[i] = xp[(size_t)i*50176];
    } else {
#pragma unroll
      for (int i = 0; i < 24; ++i) xv[i] = 0.f;
    }
    float s = 0.f, s2 = 0.f;
#pragma unroll
    for (int i = 0; i < 24; ++i){ s += xv[i]; s2 += xv[i]*xv[i]; }
    s  += __shfl_xor(s, 16);  s  += __shfl_xor(s, 32);
    s2 += __shfl_xor(s2, 16); s2 += __shfl_xor(s2, 32);
    float m = s * (1.f/96.f);
    float var = s2 * (1.f/96.f) - m*m;
    float rstd = rsqrtf(var + 1e-5f);
    unsigned* w32 = (unsigned*)(XN + t*100 + 24*lg);
    if (t < 49){
#pragma unroll
      for (int i = 0; i < 12; ++i){
        int c = 24*lg + 2*i;
        w32[i] = pk2((xv[2*i]   - m)*rstd*g1[c]   + b1[c],
                     (xv[2*i+1] - m)*rstd*g1[c+1] + b1[c+1]);
      }
    } else {
#pragma unroll
      for (int i = 0; i < 12; ++i) w32[i] = 0;
    }
  }
  __syncthreads();   // barrier 1: xn published (V reads cross-wave rows)

  // ---- ph2: QKV ----
  {
    short8 bx0 = lds8(XN + (16*w+ln)*100 + 0  + 8*lg);
    short8 bx1 = lds8(XN + (16*w+ln)*100 + 32 + 8*lg);
    short8 bx2 = lds8(XN + (16*w+ln)*100 + 64 + 8*lg);
#pragma unroll
    for (int mt = 0; mt < 6; ++mt){
      int d0 = 16*mt + 4*lg;
      f32x4 aq, ak;
#pragma unroll
      for (int r = 0; r < 4; ++r){ aq[r] = bq[d0+r]; ak[r] = bk[d0+r]; }
      aq = MFMA(gfrag(wfr +        (mt*3+0)*512 + lane*8), bx0, aq);
      aq = MFMA(gfrag(wfr +        (mt*3+1)*512 + lane*8), bx1, aq);
      aq = MFMA(gfrag(wfr +        (mt*3+2)*512 + lane*8), bx2, aq);
      ak = MFMA(gfrag(wfr + 9216 + (mt*3+0)*512 + lane*8), bx0, ak);
      ak = MFMA(gfrag(wfr + 9216 + (mt*3+1)*512 + lane*8), bx1, ak);
      ak = MFMA(gfrag(wfr + 9216 + (mt*3+2)*512 + lane*8), bx2, ak);
      st2(QS + (16*w+ln)*100 + d0, pk2(aq[0],aq[1]), pk2(aq[2],aq[3]));
      st2(KS + (16*w+ln)*100 + d0, pk2(ak[0],ak[1]), pk2(ak[2],ak[3]));
    }
#pragma unroll
    for (int f = 0; f < 6; ++f){
      int fl = f*4 + w;
      int mt = fl / 6, nt = fl % 6;
      float bvv = bv[16*nt + ln];
      f32x4 av; av[0]=bvv; av[1]=bvv; av[2]=bvv; av[3]=bvv;
#pragma unroll
      for (int kb = 0; kb < 3; ++kb)
        av = MFMA(lds8(XN + (16*mt+ln)*100 + 32*kb + 8*lg),
                  gfrag(wfr + 18432 + (nt*3+kb)*512 + lane*8), av);
      st2(VT + (16*nt+ln)*68 + 16*mt + 4*lg, pk2(av[0],av[1]), pk2(av[2],av[3]));
    }
  }
  __syncthreads();   // barrier 2: q/k/vT published. No more barriers.

  // ---- ph3: attention, P via registers+shfl ----
  const float beta  = beta_p[0];
  const float scale = 0.20412414523193150818f;
  const float gq    = __expf(-beta * EWF[16*w + ln]);
  const int  srcA   = ((lg & 1) << 5) + ln;   // lane 16*(2*(lg&1)) + ln
  const int  srcB   = srcA + 16;
  const bool hi     = (lg >= 2);

#pragma unroll
  for (int h = 0; h < 4; ++h){
    short8 bqf = (lg < 3) ? lds8(QS + (16*w+ln)*100 + 24*h + 8*lg) : zero8();
    f32x4 sva[4];
#pragma unroll
    for (int mt = 0; mt < 4; ++mt){
      f32x4 z; z[0]=0.f; z[1]=0.f; z[2]=0.f; z[3]=0.f;
      short8 af = (lg < 3) ? lds8(KS + (16*mt+ln)*100 + 24*h + 8*lg) : zero8();
      sva[mt] = MFMA(af, bqf, z);
    }
    float vv[16]; float mx = -3e38f;
#pragma unroll
    for (int mt = 0; mt < 4; ++mt)
#pragma unroll
      for (int r = 0; r < 4; ++r){
        int key = 16*mt + 4*lg + r;
        float v = (key <= 48) ? sva[mt][r]*scale : -3e38f;
        vv[mt*4+r] = v; mx = fmaxf(mx, v);
      }
    mx = fmaxf(mx, __shfl_xor(mx, 16));
    mx = fmaxf(mx, __shfl_xor(mx, 32));
    float ssum = 0.f;
#pragma unroll
    for (int i = 0; i < 16; ++i){ float e = __expf(vv[i] - mx); vv[i] = e; ssum += e; }
    ssum += __shfl_xor(ssum, 16);
    ssum += __shfl_xor(ssum, 32);
    float inv = gq / (ssum * (gq + 1e-9f));

    unsigned pu[4][2];
#pragma unroll
    for (int mt = 0; mt < 4; ++mt){
      pu[mt][0] = pk2(vv[4*mt+0]*inv, vv[4*mt+1]*inv);
      pu[mt][1] = pk2(vv[4*mt+2]*inv, vv[4*mt+3]*inv);
    }
    // Build PV B-fragments by shfl: slot j of lane(lg,ln) = P[q=16w+ln][key=32kb+8lg+j]
    unsigned a00=__shfl(pu[0][0],srcA), a01=__shfl(pu[0][1],srcA);
    unsigned a10=__shfl(pu[1][0],srcA), a11=__shfl(pu[1][1],srcA);
    unsigned b00=__shfl(pu[0][0],srcB), b01=__shfl(pu[0][1],srcB);
    unsigned b10=__shfl(pu[1][0],srcB), b11=__shfl(pu[1][1],srcB);
    short8 pf0 = mk8(hi?a10:a00, hi?a11:a01, hi?b10:b00, hi?b11:b01);
    unsigned c00=__shfl(pu[2][0],srcA), c01=__shfl(pu[2][1],srcA);
    unsigned c10=__shfl(pu[3][0],srcA), c11=__shfl(pu[3][1],srcA);
    unsigned d00=__shfl(pu[2][0],srcB), d01=__shfl(pu[2][1],srcB);
    unsigned d10=__shfl(pu[3][0],srcB), d11=__shfl(pu[3][1],srcB);
    short8 pf1 = mk8(hi?c10:c00, hi?c11:c01, hi?d10:d00, hi?d11:d01);

#pragma unroll
    for (int mt = 0; mt < 2; ++mt){
      f32x4 pv; pv[0]=0.f; pv[1]=0.f; pv[2]=0.f; pv[3]=0.f;
      pv = MFMA(lds8(VT + (24*h+16*mt+ln)*68 + 0  + 8*lg), pf0, pv);
      pv = MFMA(lds8(VT + (24*h+16*mt+ln)*68 + 32 + 8*lg), pf1, pv);
      if (!(mt == 1 && lg >= 2))
        st2(XN + (16*w+ln)*100 + 24*h + 16*mt + 4*lg, pk2(pv[0],pv[1]), pk2(pv[2],pv[3]));
    }
  }

  // ---- ph4: proj + residual -> xres (bf16, pixel-flat) ----
  {
    f32x4 po[6];
#pragma unroll
    for (int mt = 0; mt < 6; ++mt){
      int c0 = 16*mt + 4*lg;
#pragma unroll
      for (int r = 0; r < 4; ++r) po[mt][r] = bo[c0+r];
    }
#pragma unroll
    for (int kb = 0; kb < 3; ++kb){
      short8 bf_ = lds8(XN + (16*w+ln)*100 + 32*kb + 8*lg);   // own rows, all heads done
#pragma unroll
      for (int mt = 0; mt < 6; ++mt)
        po[mt] = MFMA(gfrag(wfr + 27648 + (mt*3+kb)*512 + lane*8), bf_, po[mt]);
    }
    const int t = 16*w + ln;
    if (t < 49){
      size_t pixloc = (size_t)(h0 + t/7)*224 + w0 + t%7;
      const float* xp = x + (size_t)b*96*50176 + pixloc;
      unsigned short* xo = xres + ((size_t)b*50176 + pixloc)*96;
#pragma unroll
      for (int mt = 0; mt < 6; ++mt){
        int c0 = 16*mt + 4*lg;
        float r0 = po[mt][0] + xp[(size_t)(c0+0)*50176];
        float r1 = po[mt][1] + xp[(size_t)(c0+1)*50176];
        float r2 = po[mt][2] + xp[(size_t)(c0+2)*50176];
        float r3 = po[mt][3] + xp[(size_t)(c0+3)*50176];
        st2(xo + c0, pk2(r0,r1), pk2(r2,r3));
      }
    }
  }
}

// ---------------------------------------------------------------------------
// MLP kernel: wave-independent 16-pixel tiles, 0 barriers, 4 blocks/CU.
// grid = 6272 x 256 (25088 tiles of 16 pixels).
// ---------------------------------------------------------------------------
__global__ __launch_bounds__(256, 4) void mlp_kernel(
    const unsigned short* __restrict__ xres,
    const float* __restrict__ g2, const float* __restrict__ b2,
    const float* __restrict__ bf1, const float* __restrict__ bf2,
    const unsigned short* __restrict__ wfr,
    float* __restrict__ out)
{
  __shared__ __align__(16) unsigned short XH[4][4800];  // per wave: xn2[16][100] + hs[16][200]
  const int tid = threadIdx.x, lane = tid & 63, w = tid >> 6;
  const int lg = lane >> 4, ln = lane & 15;
  unsigned short* XN2 = &XH[w][0];
  unsigned short* HS  = &XH[w][1600];

  const int tile = blockIdx.x*4 + w;
  const size_t p0 = (size_t)tile * 16;
  const int bimg = (int)(p0 / 50176);
  const size_t pixin = p0 - (size_t)bimg*50176;

  // LN2 (wave-local)
  {
    const unsigned* xp = (const unsigned*)(xres + (p0 + (size_t)ln)*96 + 24*lg);
    float xv[24];
#pragma unroll
    for (int i = 0; i < 12; ++i){
      unsigned u = xp[i];
      xv[2*i] = bfu(u); xv[2*i+1] = bfu(u >> 16);
    }
    float s = 0.f, s2 = 0.f;
#pragma unroll
    for (int i = 0; i < 24; ++i){ s += xv[i]; s2 += xv[i]*xv[i]; }
    s  += __shfl_xor(s, 16);  s  += __shfl_xor(s, 32);
    s2 += __shfl_xor(s2, 16); s2 += __shfl_xor(s2, 32);
    float m = s * (1.f/96.f);
    float var = s2 * (1.f/96.f) - m*m;
    float rstd = rsqrtf(var + 1e-5f);
    unsigned* w32 = (unsigned*)(XN2 + ln*100 + 24*lg);
#pragma unroll
    for (int i = 0; i < 12; ++i){
      int c = 24*lg + 2*i;
      w32[i] = pk2((xv[2*i]   - m)*rstd*g2[c]   + b2[c],
                   (xv[2*i+1] - m)*rstd*g2[c+1] + b2[c+1]);
    }
  }

  f32x4 oacc[6];
#pragma unroll
  for (int mt = 0; mt < 6; ++mt){
    int c0 = 16*mt + 4*lg;
#pragma unroll
    for (int r = 0; r < 4; ++r) oacc[mt][r] = bf2[c0+r];
  }

  short8 bxx0 = lds8(XN2 + ln*100 + 0  + 8*lg);
  short8 bxx1 = lds8(XN2 + ln*100 + 32 + 8*lg);
  short8 bxx2 = lds8(XN2 + ln*100 + 64 + 8*lg);

#pragma unroll
  for (int p = 0; p < 2; ++p){
#pragma unroll
    for (int mt = 0; mt < 12; ++mt){
      int hg = p*192 + 16*mt + 4*lg;
      f32x4 ha;
#pragma unroll
      for (int r = 0; r < 4; ++r) ha[r] = bf1[hg+r];
      ha = MFMA(gfrag(wfr + 36864 + ((p*12+mt)*3+0)*512 + lane*8), bxx0, ha);
      ha = MFMA(gfrag(wfr + 36864 + ((p*12+mt)*3+1)*512 + lane*8), bxx1, ha);
      ha = MFMA(gfrag(wfr + 36864 + ((p*12+mt)*3+2)*512 + lane*8), bxx2, ha);
      float e0 = 0.5f*ha[0]*(1.f + erff(ha[0]*0.70710678118654752f));
      float e1 = 0.5f*ha[1]*(1.f + erff(ha[1]*0.70710678118654752f));
      float e2 = 0.5f*ha[2]*(1.f + erff(ha[2]*0.70710678118654752f));
      float e3 = 0.5f*ha[3]*(1.f + erff(ha[3]*0.70710678118654752f));
      st2(HS + ln*200 + 16*mt + 4*lg, pk2(e0,e1), pk2(e2,e3));
    }
#pragma unroll
    for (int kb = 0; kb < 6; ++kb){
      short8 bh = lds8(HS + ln*200 + 32*kb + 8*lg);
#pragma unroll
      for (int mt = 0; mt < 6; ++mt)
        oacc[mt] = MFMA(gfrag(wfr + 73728 + (mt*12 + p*6 + kb)*512 + lane*8), bh, oacc[mt]);
    }
  }

  // epilogue: residual + store to (B,C,H,W)
  {
    const unsigned short* xr = xres + (p0 + (size_t)ln)*96;
    float* ob = out + (size_t)bimg*96*50176 + pixin + ln;
#pragma unroll
    for (int mt = 0; mt < 6; ++mt){
      int c0 = 16*mt + 4*lg;
      U2 rv = *(const U2*)(xr + c0);
      ob[(size_t)(c0+0)*50176] = oacc[mt][0] + bfu(rv.x);
      ob[(size_t)(c0+1)*50176] = oacc[mt][1] + bfu(rv.x >> 16);
      ob[(size_t)(c0+2)*50176] = oacc[mt][2] + bfu(rv.y);
      ob[(size_t)(c0+3)*50176] = oacc[mt][3] + bfu(rv.y >> 16);
    }
  }
}

extern "C" void kernel_launch(void* const* d_in, const int* in_sizes, int n_in,
                              void* d_out, int out_size, void* d_ws, size_t ws_size,
                              hipStream_t stream) {
  const float* x    = (const float*)d_in[0];
  const float* emap = (const float*)d_in[1];
  const float* beta = (const float*)d_in[2];
  const float* wq   = (const float*)d_in[3];
  const float* bq   = (const float*)d_in[4];
  const float* wk   = (const float*)d_in[5];
  const float* bk   = (const float*)d_in[6];
  const float* wv   = (const float*)d_in[7];
  const float* bv   = (const float*)d_in[8];
  const float* wo   = (const float*)d_in[9];
  const float* bo   = (const float*)d_in[10];
  const float* g1   = (const float*)d_in[11];
  const float* b1   = (const float*)d_in[12];
  const float* g2   = (const float*)d_in[13];
  const float* b2   = (const float*)d_in[14];
  const float* w1   = (const float*)d_in[15];
  const float* bf1  = (const float*)d_in[16];
  const float* w2   = (const float*)d_in[17];
  const float* bf2  = (const float*)d_in[18];

  float* out = (float*)d_out;
  unsigned short* wfr  = (unsigned short*)d_ws;                       // 221 KB fragments
  unsigned short* xres = (unsigned short*)((char*)d_ws + 262144);     // 77 MB bf16 [pix][96]

  prep_kernel<<<dim3(432), dim3(256), 0, stream>>>(wq, wk, wv, wo, w1, w2, wfr);
  attn_kernel<<<dim3(8192), dim3(256), 0, stream>>>(
      x, emap, beta, bq, bk, bv, bo, g1, b1, wfr, xres);
  mlp_kernel<<<dim3(6272), dim3(256), 0, stream>>>(
      xres, g2, b2, bf1, bf2, wfr, out);
}